// Round 10
// baseline (221.003 us; speedup 1.0000x reference)
//
#include <hip/hip_runtime.h>
#include <float.h>
#include <math.h>

#define TOKENS 8192
#define DIM    4096

typedef _Float16 v8h  __attribute__((ext_vector_type(8)));
typedef float    v4f  __attribute__((ext_vector_type(4)));

typedef __attribute__((address_space(3))) unsigned int lds_uint;
typedef const __attribute__((address_space(1))) unsigned int glob_uint;

__device__ __forceinline__ void stage16(const _Float16* g, _Float16* l) {
    // one instr: 64 lanes x 16 B -> LDS at (wave-uniform base + lane*16)
    __builtin_amdgcn_global_load_lds((glob_uint*)g, (lds_uint*)l, 16, 0, 0);
}

// ---------------------------------------------------------------------------
// Prep: fp16 hi/lo split B-fragments of W in d_ws (1 MB) + zero the 64
// per-token-group completion counters (deterministic re-init every call).
// WF[chunk(128)][term(2)][et(4)][lane(64)][8]:
//   B[k][n] with n = et*16 + (lane&15), k = chunk*32 + (lane>>4)*8 + j
// ---------------------------------------------------------------------------
__global__ __launch_bounds__(256) void prep_w_kernel(
    const float* __restrict__ W, _Float16* __restrict__ WF,
    unsigned int* __restrict__ cnt) {
    int n = blockIdx.x * 256 + threadIdx.x;   // 32768
    if (n < 64) cnt[n] = 0;                   // reset completion counters
    int chunk = n >> 8;
    int et    = (n >> 6) & 3;
    int lane  = n & 63;
    int e  = et * 16 + (lane & 15);
    int k0 = chunk * 32 + (lane >> 4) * 8;
    const float* src = W + (size_t)e * DIM + k0;
    v8h h, l;
    #pragma unroll
    for (int j = 0; j < 8; ++j) {
        float w = src[j];
        _Float16 wh = (_Float16)w;
        h[j] = wh;
        l[j] = (_Float16)((w - (float)wh) * 2048.0f);
    }
    size_t base = (size_t)chunk * 4096 + (size_t)et * 512 + (size_t)lane * 8;
    *(v8h*)(WF + base)        = h;
    *(v8h*)(WF + base + 2048) = l;
}

// ---- helpers (all names/indices compile-time) ------------------------------
#define LOAD_A(Aa, Ab, cc) do {                                               \
    const float* ap_ = abase + (cc) * 32;                                     \
    Aa = __builtin_nontemporal_load((const v4f*)ap_);       /* x: no reuse */ \
    Ab = __builtin_nontemporal_load((const v4f*)(ap_ + 4));                   \
} while (0)

// stage chunk cc's 8 KB slab into buf[BI]; each wave stages its 1 KB portion
#define STAGE(BI, cc) stage16(sbase + (size_t)(cc) * 4096, &buf[BI][wq * 512])

#define CVT1(f, j) {                                                          \
    _Float16 h_ = (_Float16)(f);                                              \
    ah[j] = h_;                                                               \
    al[j] = (_Float16)(((f) - (float)h_) * 2048.0f);                          \
}
#define CVT(Aa, Ab) do {                                                      \
    CVT1(Aa[0], 0) CVT1(Aa[1], 1) CVT1(Aa[2], 2) CVT1(Aa[3], 3)               \
    CVT1(Ab[0], 4) CVT1(Ab[1], 5) CVT1(Ab[2], 6) CVT1(Ab[3], 7)               \
} while (0)

#define MFMA16(a, b, c) __builtin_amdgcn_mfma_f32_16x16x32_f16(a, b, c, 0, 0, 0)

// compute chunk from buf[BI]: 8 conflict-free ds_read_b128 + 12 MFMA
#define COMPC(BI, Aa, Ab) do {                                                \
    CVT(Aa, Ab);                                                              \
    const _Float16* bp_ = &buf[BI][0] + (size_t)lane * 8;                     \
    v8h h0_ = *(const v8h*)(bp_);                                             \
    v8h h1_ = *(const v8h*)(bp_ + 512);                                       \
    v8h h2_ = *(const v8h*)(bp_ + 1024);                                      \
    v8h h3_ = *(const v8h*)(bp_ + 1536);                                      \
    v8h l0_ = *(const v8h*)(bp_ + 2048);                                      \
    v8h l1_ = *(const v8h*)(bp_ + 2560);                                      \
    v8h l2_ = *(const v8h*)(bp_ + 3072);                                      \
    v8h l3_ = *(const v8h*)(bp_ + 3584);                                      \
    acc1[0] = MFMA16(ah, h0_, acc1[0]);                                       \
    acc1[1] = MFMA16(ah, h1_, acc1[1]);                                       \
    acc1[2] = MFMA16(ah, h2_, acc1[2]);                                       \
    acc1[3] = MFMA16(ah, h3_, acc1[3]);                                       \
    acc2[0] = MFMA16(al, h0_, acc2[0]);  acc2[0] = MFMA16(ah, l0_, acc2[0]);  \
    acc2[1] = MFMA16(al, h1_, acc2[1]);  acc2[1] = MFMA16(ah, l1_, acc2[1]);  \
    acc2[2] = MFMA16(al, h2_, acc2[2]);  acc2[2] = MFMA16(ah, l2_, acc2[2]);  \
    acc2[3] = MFMA16(al, h3_, acc2[3]);  acc2[3] = MFMA16(ah, l3_, acc2[3]);  \
} while (0)

#define BARRIER_KEEP(n) do {                                                  \
    __builtin_amdgcn_sched_barrier(0);                                        \
    asm volatile("s_waitcnt vmcnt(" #n ")" ::: "memory");                     \
    __builtin_amdgcn_sched_barrier(0);                                        \
    __builtin_amdgcn_s_barrier();                                             \
    __builtin_amdgcn_sched_barrier(0);                                        \
} while (0)

// full iter: stage B(c+1) first, then A(c+2); end: drain stage, keep 2 A loads
#define ITER_FULL(c, ACa, ACb, ALa, ALb, BCUR, BNXT) do {                     \
    STAGE(BNXT, (c) + 1);                                                     \
    LOAD_A(ALa, ALb, (c) + 2);                                                \
    COMPC(BCUR, ACa, ACb);                                                    \
    BARRIER_KEEP(2);                                                          \
} while (0)

#define ITER_STAGE_ONLY(c, ACa, ACb, BCUR, BNXT) do {                         \
    STAGE(BNXT, (c) + 1);                                                     \
    COMPC(BCUR, ACa, ACb);                                                    \
    BARRIER_KEEP(0);                                                          \
} while (0)

// ---------------------------------------------------------------------------
// Fused: partial logits + last-block top-2 reduction.
// Grid = 512 blocks x 512 thr (8 waves = 8 M-tiles of 16 tokens).
// tg = blockIdx&63 (token group, 128 tokens), kg = blockIdx>>6 (K-slice) so
// the 8 kg-blocks of one tg are 64 apart -> same XCD under %8 round-robin
// (placement is a speed heuristic only). Last finishing block per tg reduces.
// ---------------------------------------------------------------------------
__global__ __launch_bounds__(512, 4) void logits_fused_kernel(
    const float* __restrict__ x,
    const _Float16* __restrict__ WF,
    float* __restrict__ P,
    unsigned int* __restrict__ cnt,
    float* __restrict__ out) {

    __shared__ _Float16 buf[2][4096];     // 2 x 8 KB double-buffered B slab
    __shared__ int amLast;

    const int tid  = threadIdx.x;
    const int wq   = tid >> 6;            // wave = M-tile
    const int lane = tid & 63;
    const int tg   = (int)(blockIdx.x & 63);      // token group (128 tokens)
    const int kg   = (int)(blockIdx.x >> 6);      // K-slice (512 d)
    const int tok0 = tg * 128 + wq * 16;
    const int art  = lane & 15;           // token row within M-tile
    const int akg  = lane >> 4;           // k-group
    const int chunk0 = kg * 16;

    const float*    abase = x  + (size_t)(tok0 + art) * DIM + chunk0 * 32 + akg * 8;
    const _Float16* sbase = WF + (size_t)chunk0 * 4096 + (size_t)tid * 8;  // stage src

    v4f acc1[4], acc2[4];
    #pragma unroll
    for (int e4 = 0; e4 < 4; ++e4) { acc1[e4] = (v4f)0.0f; acc2[e4] = (v4f)0.0f; }

    v4f A0a, A0b, A1a, A1b, A2a, A2b;
    v8h ah, al;

    // prologue: stage chunk 0, A depth-2
    STAGE(0, 0);
    LOAD_A(A0a, A0b, 0);
    LOAD_A(A1a, A1b, 1);
    BARRIER_KEEP(4);                      // drain stage; keep the 4 A loads

    ITER_FULL(0,  A0a, A0b, A2a, A2b, 0, 1);
    ITER_FULL(1,  A1a, A1b, A0a, A0b, 1, 0);
    ITER_FULL(2,  A2a, A2b, A1a, A1b, 0, 1);
    ITER_FULL(3,  A0a, A0b, A2a, A2b, 1, 0);
    ITER_FULL(4,  A1a, A1b, A0a, A0b, 0, 1);
    ITER_FULL(5,  A2a, A2b, A1a, A1b, 1, 0);
    ITER_FULL(6,  A0a, A0b, A2a, A2b, 0, 1);
    ITER_FULL(7,  A1a, A1b, A0a, A0b, 1, 0);
    ITER_FULL(8,  A2a, A2b, A1a, A1b, 0, 1);
    ITER_FULL(9,  A0a, A0b, A2a, A2b, 1, 0);
    ITER_FULL(10, A1a, A1b, A0a, A0b, 0, 1);
    ITER_FULL(11, A2a, A2b, A1a, A1b, 1, 0);
    ITER_FULL(12, A0a, A0b, A2a, A2b, 0, 1);
    ITER_FULL(13, A1a, A1b, A0a, A0b, 1, 0);
    ITER_STAGE_ONLY(14, A2a, A2b, 0, 1);  // stage chunk 15; no more A loads
    COMPC(1, A0a, A0b);                   // chunk 15

    // write partial logits: C/D layout col=lane&15(expert), row=(lane>>4)*4+r
    const float inv2048 = 1.0f / 2048.0f;
    #pragma unroll
    for (int e4 = 0; e4 < 4; ++e4) {
        #pragma unroll
        for (int r = 0; r < 4; ++r) {
            float v = acc1[e4][r] + acc2[e4][r] * inv2048;
            P[((size_t)kg * TOKENS + tok0 + akg * 4 + r) * 64 + e4 * 16 + art] = v;
        }
    }

    // ---- last-block-done handoff (standard threadfence-reduction pattern) --
    __threadfence();                      // all threads: release P stores
    __syncthreads();                      // everyone fenced before the atomic
    if (tid == 0) amLast = (atomicAdd(cnt + tg, 1u) == 7u);
    __syncthreads();
    if (!amLast) return;
    __threadfence();                      // acquire: other blocks' P stores

    // ---- fused reduce: this block's 128 tokens; wave wq owns 16 tokens ----
    #pragma unroll 2
    for (int tt = 0; tt < 16; ++tt) {
        int gt = tg * 128 + wq * 16 + tt;
        float v = 0.f;
        #pragma unroll
        for (int k2 = 0; k2 < 8; ++k2)
            v += P[((size_t)k2 * TOKENS + gt) * 64 + lane];

        // argmax #1 (tie-break: smaller index, matching jax.lax.top_k)
        float bv = v; int bi = lane;
        #pragma unroll
        for (int off = 32; off >= 1; off >>= 1) {
            float ov = __shfl_xor(bv, off);
            int   oi = __shfl_xor(bi, off);
            if (ov > bv || (ov == bv && oi < bi)) { bv = ov; bi = oi; }
        }
        // argmax #2 (exclude bi)
        float v2 = (lane == bi) ? -FLT_MAX : v;
        float bv2 = v2; int bi2 = lane;
        #pragma unroll
        for (int off = 32; off >= 1; off >>= 1) {
            float ov = __shfl_xor(bv2, off);
            int   oi = __shfl_xor(bi2, off);
            if (ov > bv2 || (ov == bv2 && oi < bi2)) { bv2 = ov; bi2 = oi; }
        }

        if (lane == 0) {
            // top-2 renormalized softmax cancels: g0 = 1/(1+exp(l1-l0))
            float g0 = 1.0f / (1.0f + expf(bv2 - bv));
            out[gt]              = (float)bi;
            out[TOKENS + gt]     = (float)bi2;
            out[2 * TOKENS + gt] = g0;
            out[3 * TOKENS + gt] = 1.0f - g0;
        }
    }
}

extern "C" void kernel_launch(void* const* d_in, const int* in_sizes, int n_in,
                              void* d_out, int out_size, void* d_ws, size_t ws_size,
                              hipStream_t stream) {
    const float* x = (const float*)d_in[0];   // [8192, 4096] fp32
    const float* W = (const float*)d_in[1];   // [64, 4096] fp32
    float* out     = (float*)d_out;           // [4 * 8192] fp32
    _Float16* WF   = (_Float16*)d_ws;                            // 1 MB fragments
    float* P       = (float*)((char*)d_ws + (1 << 20));          // 16 MB partials
    unsigned int* cnt = (unsigned int*)((char*)d_ws + (17 << 20)); // 64 counters

    prep_w_kernel<<<128, 256, 0, stream>>>(W, WF, cnt);
    logits_fused_kernel<<<512, 512, 0, stream>>>(x, WF, P, cnt, out);
}

// Round 11
// 47.915 us; speedup vs baseline: 4.6124x; 4.6124x over previous
//
#include <hip/hip_runtime.h>
#include <float.h>
#include <math.h>

#define TOKENS 8192
#define DIM    4096

typedef _Float16 v8h  __attribute__((ext_vector_type(8)));
typedef _Float16 v4h  __attribute__((ext_vector_type(4)));
typedef float    v4f  __attribute__((ext_vector_type(4)));

// ---------------------------------------------------------------------------
// Single GEMM kernel, W converted in-kernel (no prep dispatch).
// Grid = 512 blocks x 512 thr (8 waves = 8 M-tiles of 16 tokens = 128 tok).
// kg = blockIdx&7 -> K-slice of 16 chunks (K=32 each). Per chunk the block
// stages W's fragment slab into LDS: global fp32 -> reg -> hi/lo fp16 ->
// ds_write. All staging is compiler-tracked: the per-iter barrier only needs
// lgkmcnt(0); the A-prefetch queue is NEVER force-drained.
// Fragment slab layout (halfs): hi[et*512 + lr*8 + j], lo at +2048, where
// B[k][n]: n = et*16 + (lr&15), k = chunk*32 + (lr>>4)*8 + j.
// ---------------------------------------------------------------------------

#define LOAD_A(Aa, Ab, cc) do {                                               \
    const float* ap_ = abase + (cc) * 32;                                     \
    Aa = __builtin_nontemporal_load((const v4f*)ap_);       /* x: no reuse */ \
    Ab = __builtin_nontemporal_load((const v4f*)(ap_ + 4));                   \
} while (0)

#define LOAD_W(WV, cc) do { WV = *(const v4f*)(wsrc + (cc) * 32); } while (0)

// convert this thread's 4 W floats to hi/lo fp16 and write to buf[BI]
#define WRITE_W(BI, WV) do {                                                  \
    v4h hh_, ll_;                                                             \
    _Pragma("unroll")                                                         \
    for (int j_ = 0; j_ < 4; ++j_) {                                          \
        _Float16 h_ = (_Float16)WV[j_];                                       \
        hh_[j_] = h_;                                                         \
        ll_[j_] = (_Float16)((WV[j_] - (float)h_) * 2048.0f);                 \
    }                                                                         \
    *(v4h*)(&buf[BI][wofs])        = hh_;                                     \
    *(v4h*)(&buf[BI][2048 + wofs]) = ll_;                                     \
} while (0)

#define CVT1(f, j) {                                                          \
    _Float16 h_ = (_Float16)(f);                                              \
    ah[j] = h_;                                                               \
    al[j] = (_Float16)(((f) - (float)h_) * 2048.0f);                          \
}
#define CVT(Aa, Ab) do {                                                      \
    CVT1(Aa[0], 0) CVT1(Aa[1], 1) CVT1(Aa[2], 2) CVT1(Aa[3], 3)               \
    CVT1(Ab[0], 4) CVT1(Ab[1], 5) CVT1(Ab[2], 6) CVT1(Ab[3], 7)               \
} while (0)

#define MFMA16(a, b, c) __builtin_amdgcn_mfma_f32_16x16x32_f16(a, b, c, 0, 0, 0)

// compute chunk from buf[BI]: 8 conflict-free ds_read_b128 + 12 MFMA
#define COMPC(BI, Aa, Ab) do {                                                \
    CVT(Aa, Ab);                                                              \
    const _Float16* bp_ = &buf[BI][0] + (size_t)lane * 8;                     \
    v8h h0_ = *(const v8h*)(bp_);                                             \
    v8h h1_ = *(const v8h*)(bp_ + 512);                                       \
    v8h h2_ = *(const v8h*)(bp_ + 1024);                                      \
    v8h h3_ = *(const v8h*)(bp_ + 1536);                                      \
    v8h l0_ = *(const v8h*)(bp_ + 2048);                                      \
    v8h l1_ = *(const v8h*)(bp_ + 2560);                                      \
    v8h l2_ = *(const v8h*)(bp_ + 3072);                                      \
    v8h l3_ = *(const v8h*)(bp_ + 3584);                                      \
    acc1[0] = MFMA16(ah, h0_, acc1[0]);                                       \
    acc1[1] = MFMA16(ah, h1_, acc1[1]);                                       \
    acc1[2] = MFMA16(ah, h2_, acc1[2]);                                       \
    acc1[3] = MFMA16(ah, h3_, acc1[3]);                                       \
    acc2[0] = MFMA16(al, h0_, acc2[0]);  acc2[0] = MFMA16(ah, l0_, acc2[0]);  \
    acc2[1] = MFMA16(al, h1_, acc2[1]);  acc2[1] = MFMA16(ah, l1_, acc2[1]);  \
    acc2[2] = MFMA16(al, h2_, acc2[2]);  acc2[2] = MFMA16(ah, l2_, acc2[2]);  \
    acc2[3] = MFMA16(al, h3_, acc2[3]);  acc2[3] = MFMA16(ah, l3_, acc2[3]);  \
} while (0)

// barrier: only LDS visibility required (staging is ds_write, compiler-tracked
// A/W loads wait at their uses) -> A-prefetch stays in flight across barriers
#define BARRIER_LDS() do {                                                    \
    asm volatile("s_waitcnt lgkmcnt(0)" ::: "memory");                        \
    __builtin_amdgcn_sched_barrier(0);                                        \
    __builtin_amdgcn_s_barrier();                                            \
    __builtin_amdgcn_sched_barrier(0);                                        \
} while (0)

// full iter: load W(c+1)+A(c+2); compute chunk c from BCUR; write W(c+1)->BNXT
#define ITER_FULL(c, ACa, ACb, ALa, ALb, BCUR, BNXT) do {                     \
    LOAD_W(wv, (c) + 1);                                                      \
    LOAD_A(ALa, ALb, (c) + 2);                                                \
    COMPC(BCUR, ACa, ACb);                                                    \
    WRITE_W(BNXT, wv);                                                        \
    BARRIER_LDS();                                                            \
} while (0)

#define ITER_NOA(c, ACa, ACb, BCUR, BNXT) do {   /* tail: no A load */        \
    LOAD_W(wv, (c) + 1);                                                      \
    COMPC(BCUR, ACa, ACb);                                                    \
    WRITE_W(BNXT, wv);                                                        \
    BARRIER_LDS();                                                            \
} while (0)

__global__ __launch_bounds__(512, 4) void logits_kernel(
    const float* __restrict__ x,
    const float* __restrict__ W,
    float* __restrict__ P) {

    __shared__ _Float16 buf[2][4096];     // 2 x 8 KB double-buffered B slab

    const int tid  = threadIdx.x;
    const int wq   = tid >> 6;            // wave = M-tile
    const int lane = tid & 63;
    const int kg   = (int)(blockIdx.x & 7);       // K-slice (512 d, 16 chunks)
    const int tg   = (int)(blockIdx.x >> 3);      // token group (128 tokens)
    const int tok0 = tg * 128 + wq * 16;
    const int art  = lane & 15;           // token row within M-tile
    const int akg  = lane >> 4;           // k-group
    const int chunk0 = kg * 16;

    const float* abase = x + (size_t)(tok0 + art) * DIM + chunk0 * 32 + akg * 8;

    // W stage addressing: thread handles fragment row (et, lr), half of 8 k's
    const int row  = tid >> 1, half = tid & 1;
    const int et   = row >> 6, lr = row & 63;
    const int we   = et * 16 + (lr & 15);
    const float* wsrc = W + (size_t)we * DIM + chunk0 * 32 + (lr >> 4) * 8 + half * 4;
    const int wofs = et * 512 + lr * 8 + half * 4;   // halfs offset in slab

    v4f acc1[4], acc2[4];
    #pragma unroll
    for (int e4 = 0; e4 < 4; ++e4) { acc1[e4] = (v4f)0.0f; acc2[e4] = (v4f)0.0f; }

    v4f A0a, A0b, A1a, A1b, A2a, A2b, wv;
    v8h ah, al;

    // prologue: stage chunk 0 into buf0, A depth-2
    LOAD_W(wv, 0);
    LOAD_A(A0a, A0b, 0);
    LOAD_A(A1a, A1b, 1);
    WRITE_W(0, wv);
    BARRIER_LDS();

    ITER_FULL(0,  A0a, A0b, A2a, A2b, 0, 1);
    ITER_FULL(1,  A1a, A1b, A0a, A0b, 1, 0);
    ITER_FULL(2,  A2a, A2b, A1a, A1b, 0, 1);
    ITER_FULL(3,  A0a, A0b, A2a, A2b, 1, 0);
    ITER_FULL(4,  A1a, A1b, A0a, A0b, 0, 1);
    ITER_FULL(5,  A2a, A2b, A1a, A1b, 1, 0);
    ITER_FULL(6,  A0a, A0b, A2a, A2b, 0, 1);
    ITER_FULL(7,  A1a, A1b, A0a, A0b, 1, 0);
    ITER_FULL(8,  A2a, A2b, A1a, A1b, 0, 1);
    ITER_FULL(9,  A0a, A0b, A2a, A2b, 1, 0);
    ITER_FULL(10, A1a, A1b, A0a, A0b, 0, 1);
    ITER_FULL(11, A2a, A2b, A1a, A1b, 1, 0);
    ITER_FULL(12, A0a, A0b, A2a, A2b, 0, 1);
    ITER_FULL(13, A1a, A1b, A0a, A0b, 1, 0);
    ITER_NOA(14, A2a, A2b, 0, 1);         // stage chunk 15; no more A loads
    COMPC(1, A0a, A0b);                   // chunk 15

    // write partial logits: C/D layout col=lane&15(expert), row=(lane>>4)*4+r
    const float inv2048 = 1.0f / 2048.0f;
    #pragma unroll
    for (int e4 = 0; e4 < 4; ++e4) {
        #pragma unroll
        for (int r = 0; r < 4; ++r) {
            float v = acc1[e4][r] + acc2[e4][r] * inv2048;
            P[((size_t)kg * TOKENS + tok0 + akg * 4 + r) * 64 + e4 * 16 + art] = v;
        }
    }
}

// ---------------------------------------------------------------------------
// Pass 2: logits = sum of 8 K-slice partials; top-2 + gates. 512 x 256.
// ---------------------------------------------------------------------------
__global__ __launch_bounds__(256) void reduce_topk_kernel(
    const float* __restrict__ P, float* __restrict__ out) {
    const int wq   = threadIdx.x >> 6;
    const int lane = threadIdx.x & 63;
    #pragma unroll
    for (int tt = 0; tt < 4; ++tt) {
        int gt = blockIdx.x * 16 + wq * 4 + tt;
        float v = 0.f;
        #pragma unroll
        for (int kg = 0; kg < 8; ++kg)
            v += P[((size_t)kg * TOKENS + gt) * 64 + lane];

        // argmax #1 (tie-break: smaller index, matching jax.lax.top_k)
        float bv = v; int bi = lane;
        #pragma unroll
        for (int off = 32; off >= 1; off >>= 1) {
            float ov = __shfl_xor(bv, off);
            int   oi = __shfl_xor(bi, off);
            if (ov > bv || (ov == bv && oi < bi)) { bv = ov; bi = oi; }
        }
        // argmax #2 (exclude bi)
        float v2 = (lane == bi) ? -FLT_MAX : v;
        float bv2 = v2; int bi2 = lane;
        #pragma unroll
        for (int off = 32; off >= 1; off >>= 1) {
            float ov = __shfl_xor(bv2, off);
            int   oi = __shfl_xor(bi2, off);
            if (ov > bv2 || (ov == bv2 && oi < bi2)) { bv2 = ov; bi2 = oi; }
        }

        if (lane == 0) {
            // top-2 renormalized softmax cancels: g0 = 1/(1+exp(l1-l0))
            float g0 = 1.0f / (1.0f + expf(bv2 - bv));
            out[gt]              = (float)bi;
            out[TOKENS + gt]     = (float)bi2;
            out[2 * TOKENS + gt] = g0;
            out[3 * TOKENS + gt] = 1.0f - g0;
        }
    }
}

extern "C" void kernel_launch(void* const* d_in, const int* in_sizes, int n_in,
                              void* d_out, int out_size, void* d_ws, size_t ws_size,
                              hipStream_t stream) {
    const float* x = (const float*)d_in[0];   // [8192, 4096] fp32
    const float* W = (const float*)d_in[1];   // [64, 4096] fp32
    float* out     = (float*)d_out;           // [4 * 8192] fp32
    float* P       = (float*)d_ws;            // 16 MB partial logits

    logits_kernel<<<512, 512, 0, stream>>>(x, W, P);
    reduce_topk_kernel<<<512, 256, 0, stream>>>(P, out);
}

// Round 12
// 40.830 us; speedup vs baseline: 5.4128x; 1.1735x over previous
//
#include <hip/hip_runtime.h>
#include <float.h>
#include <math.h>

#define TOKENS 8192
#define DIM    4096

typedef _Float16 v8h  __attribute__((ext_vector_type(8)));
typedef float    v4f  __attribute__((ext_vector_type(4)));

typedef __attribute__((address_space(3))) unsigned int lds_uint;
typedef const __attribute__((address_space(1))) unsigned int glob_uint;

__device__ __forceinline__ void stage16(const _Float16* g, _Float16* l) {
    // one instr: 64 lanes x 16 B -> LDS at (wave-uniform base + lane*16)
    __builtin_amdgcn_global_load_lds((glob_uint*)g, (lds_uint*)l, 16, 0, 0);
}

// ---------------------------------------------------------------------------
// Prep: fp16 hi/lo split B-fragments of W in d_ws (1 MB).
// WF[chunk(128)][term(2)][et(4)][lane(64)][8]:
//   B[k][n] with n = et*16 + (lane&15), k = chunk*32 + (lane>>4)*8 + j
// One chunk slab = 4096 halfs = 8 KB, contiguous.
// ---------------------------------------------------------------------------
__global__ __launch_bounds__(256) void prep_w_kernel(
    const float* __restrict__ W, _Float16* __restrict__ WF) {
    int n = blockIdx.x * 256 + threadIdx.x;   // 32768
    int chunk = n >> 8;
    int et    = (n >> 6) & 3;
    int lane  = n & 63;
    int e  = et * 16 + (lane & 15);
    int k0 = chunk * 32 + (lane >> 4) * 8;
    const float* src = W + (size_t)e * DIM + k0;
    v8h h, l;
    #pragma unroll
    for (int j = 0; j < 8; ++j) {
        float w = src[j];
        _Float16 wh = (_Float16)w;
        h[j] = wh;
        l[j] = (_Float16)((w - (float)wh) * 2048.0f);
    }
    size_t base = (size_t)chunk * 4096 + (size_t)et * 512 + (size_t)lane * 8;
    *(v8h*)(WF + base)        = h;
    *(v8h*)(WF + base + 2048) = l;
}

// ---- helpers (all names/indices compile-time) ------------------------------
#define LOAD_A(Aa, Ab, cc) do {                                               \
    const float* ap_ = abase + (cc) * 32;                                     \
    Aa = *(const v4f*)ap_;                                                    \
    Ab = *(const v4f*)(ap_ + 4);                                              \
} while (0)

// stage chunk cc's 8 KB slab into buf[BI]; each wave stages its 1 KB portion
#define STAGE(BI, cc) stage16(sbase + (size_t)(cc) * 4096, &buf[BI][wq * 512])

#define CVT1(f, j) {                                                          \
    _Float16 h_ = (_Float16)(f);                                              \
    ah[j] = h_;                                                               \
    al[j] = (_Float16)(((f) - (float)h_) * 2048.0f);                          \
}
#define CVT(Aa, Ab) do {                                                      \
    CVT1(Aa[0], 0) CVT1(Aa[1], 1) CVT1(Aa[2], 2) CVT1(Aa[3], 3)               \
    CVT1(Ab[0], 4) CVT1(Ab[1], 5) CVT1(Ab[2], 6) CVT1(Ab[3], 7)               \
} while (0)

#define MFMA16(a, b, c) __builtin_amdgcn_mfma_f32_16x16x32_f16(a, b, c, 0, 0, 0)

// compute chunk from buf[BI]: 8 conflict-free ds_read_b128 + 12 MFMA
#define COMPC(BI, Aa, Ab) do {                                                \
    CVT(Aa, Ab);                                                              \
    const _Float16* bp_ = &buf[BI][0] + (size_t)lane * 8;                     \
    v8h h0_ = *(const v8h*)(bp_);                                             \
    v8h h1_ = *(const v8h*)(bp_ + 512);                                       \
    v8h h2_ = *(const v8h*)(bp_ + 1024);                                      \
    v8h h3_ = *(const v8h*)(bp_ + 1536);                                      \
    v8h l0_ = *(const v8h*)(bp_ + 2048);                                      \
    v8h l1_ = *(const v8h*)(bp_ + 2560);                                      \
    v8h l2_ = *(const v8h*)(bp_ + 3072);                                      \
    v8h l3_ = *(const v8h*)(bp_ + 3584);                                      \
    acc1[0] = MFMA16(ah, h0_, acc1[0]);                                       \
    acc1[1] = MFMA16(ah, h1_, acc1[1]);                                       \
    acc1[2] = MFMA16(ah, h2_, acc1[2]);                                       \
    acc1[3] = MFMA16(ah, h3_, acc1[3]);                                       \
    acc2[0] = MFMA16(al, h0_, acc2[0]);  acc2[0] = MFMA16(ah, l0_, acc2[0]);  \
    acc2[1] = MFMA16(al, h1_, acc2[1]);  acc2[1] = MFMA16(ah, l1_, acc2[1]);  \
    acc2[2] = MFMA16(al, h2_, acc2[2]);  acc2[2] = MFMA16(ah, l2_, acc2[2]);  \
    acc2[3] = MFMA16(al, h3_, acc2[3]);  acc2[3] = MFMA16(ah, l3_, acc2[3]);  \
} while (0)

#define BARRIER_KEEP(n) do {                                                  \
    __builtin_amdgcn_sched_barrier(0);                                        \
    asm volatile("s_waitcnt vmcnt(" #n ")" ::: "memory");                     \
    __builtin_amdgcn_sched_barrier(0);                                        \
    __builtin_amdgcn_s_barrier();                                             \
    __builtin_amdgcn_sched_barrier(0);                                        \
} while (0)

// full iter: stage B(c+2) into the 2-ahead buffer, load A(c+2), compute c.
// vmcnt(5) retires EXACTLY stage(c+1) (queue: st(c+1), A(c+1)x2, st(c+2),
// A(c+2)x2) -> the stage gets a full iteration of latency cover; the A
// pipeline is never force-drained (compiler's reg-dep waits handle A use).
#define ITER_FULL(c, ACa, ACb, ALa, ALb, BCUR, BNXT) do {                     \
    STAGE(BNXT, (c) + 2);                                                     \
    LOAD_A(ALa, ALb, (c) + 2);                                                \
    COMPC(BCUR, ACa, ACb);                                                    \
    BARRIER_KEEP(5);                                                          \
} while (0)

// ---------------------------------------------------------------------------
// Pass 1: partial logits. 512 blocks x 512 thr (8 waves = 8 M-tiles of 16
// tokens -> 128 tokens/block). Block (tg, kg) covers K-slice kg (16 chunks).
// All 8 waves consume the SAME staged B chunk; kg == XCD under %8 dispatch
// so each XCD keeps its 128 KB WF slice L2-resident.
// ---------------------------------------------------------------------------
__global__ __launch_bounds__(512, 4) void logits_kernel(
    const float* __restrict__ x,
    const _Float16* __restrict__ WF,
    float* __restrict__ P) {

    __shared__ _Float16 buf[3][4096];     // 3 x 8 KB triple-buffered B slab

    const int tid  = threadIdx.x;
    const int wq   = tid >> 6;            // wave = M-tile
    const int lane = tid & 63;
    const int kg   = (int)(blockIdx.x & 7);       // K-slice (512 d)
    const int tg   = (int)(blockIdx.x >> 3);      // token group (128 tokens)
    const int tok0 = tg * 128 + wq * 16;
    const int art  = lane & 15;           // token row within M-tile
    const int akg  = lane >> 4;           // k-group
    const int chunk0 = kg * 16;

    const float*    abase = x  + (size_t)(tok0 + art) * DIM + chunk0 * 32 + akg * 8;
    const _Float16* sbase = WF + (size_t)chunk0 * 4096 + (size_t)tid * 8;  // stage src

    v4f acc1[4], acc2[4];
    #pragma unroll
    for (int e4 = 0; e4 < 4; ++e4) { acc1[e4] = (v4f)0.0f; acc2[e4] = (v4f)0.0f; }

    v4f A0a, A0b, A1a, A1b, A2a, A2b;
    v8h ah, al;

    // prologue: st0, A0, A1, st1 (order keeps A0-use wait from draining st1);
    // vmcnt(5) retires exactly st0.
    STAGE(0, 0);
    LOAD_A(A0a, A0b, 0);
    LOAD_A(A1a, A1b, 1);
    STAGE(1, 1);
    BARRIER_KEEP(5);

    ITER_FULL(0,  A0a, A0b, A2a, A2b, 0, 2);
    ITER_FULL(1,  A1a, A1b, A0a, A0b, 1, 0);
    ITER_FULL(2,  A2a, A2b, A1a, A1b, 2, 1);
    ITER_FULL(3,  A0a, A0b, A2a, A2b, 0, 2);
    ITER_FULL(4,  A1a, A1b, A0a, A0b, 1, 0);
    ITER_FULL(5,  A2a, A2b, A1a, A1b, 2, 1);
    ITER_FULL(6,  A0a, A0b, A2a, A2b, 0, 2);
    ITER_FULL(7,  A1a, A1b, A0a, A0b, 1, 0);
    ITER_FULL(8,  A2a, A2b, A1a, A1b, 2, 1);
    ITER_FULL(9,  A0a, A0b, A2a, A2b, 0, 2);
    ITER_FULL(10, A1a, A1b, A0a, A0b, 1, 0);
    ITER_FULL(11, A2a, A2b, A1a, A1b, 2, 1);
    ITER_FULL(12, A0a, A0b, A2a, A2b, 0, 2);
    ITER_FULL(13, A1a, A1b, A0a, A0b, 1, 0);   // stages chunk 15 -> buf0, loads A(15)->A0
    // body(14): no stage/loads; vmcnt(2) retires st(15), keeps A(15)
    COMPC(2, A2a, A2b);
    BARRIER_KEEP(2);
    // body(15): last chunk
    COMPC(0, A0a, A0b);

    // write partial logits: C/D layout col=lane&15(expert), row=(lane>>4)*4+r
    const float inv2048 = 1.0f / 2048.0f;
    #pragma unroll
    for (int e4 = 0; e4 < 4; ++e4) {
        #pragma unroll
        for (int r = 0; r < 4; ++r) {
            float v = acc1[e4][r] + acc2[e4][r] * inv2048;
            P[((size_t)kg * TOKENS + tok0 + akg * 4 + r) * 64 + e4 * 16 + art] = v;
        }
    }
}

// ---------------------------------------------------------------------------
// Pass 2: logits = sum of 8 K-slice partials; top-2 + gates. 512 x 256.
// ---------------------------------------------------------------------------
__global__ __launch_bounds__(256) void reduce_topk_kernel(
    const float* __restrict__ P, float* __restrict__ out) {
    const int wq   = threadIdx.x >> 6;
    const int lane = threadIdx.x & 63;
    #pragma unroll
    for (int tt = 0; tt < 4; ++tt) {
        int gt = blockIdx.x * 16 + wq * 4 + tt;
        float v = 0.f;
        #pragma unroll
        for (int kg = 0; kg < 8; ++kg)
            v += P[((size_t)kg * TOKENS + gt) * 64 + lane];

        // argmax #1 (tie-break: smaller index, matching jax.lax.top_k)
        float bv = v; int bi = lane;
        #pragma unroll
        for (int off = 32; off >= 1; off >>= 1) {
            float ov = __shfl_xor(bv, off);
            int   oi = __shfl_xor(bi, off);
            if (ov > bv || (ov == bv && oi < bi)) { bv = ov; bi = oi; }
        }
        // argmax #2 (exclude bi)
        float v2 = (lane == bi) ? -FLT_MAX : v;
        float bv2 = v2; int bi2 = lane;
        #pragma unroll
        for (int off = 32; off >= 1; off >>= 1) {
            float ov = __shfl_xor(bv2, off);
            int   oi = __shfl_xor(bi2, off);
            if (ov > bv2 || (ov == bv2 && oi < bi2)) { bv2 = ov; bi2 = oi; }
        }

        if (lane == 0) {
            // top-2 renormalized softmax cancels: g0 = 1/(1+exp(l1-l0))
            float g0 = 1.0f / (1.0f + expf(bv2 - bv));
            out[gt]              = (float)bi;
            out[TOKENS + gt]     = (float)bi2;
            out[2 * TOKENS + gt] = g0;
            out[3 * TOKENS + gt] = 1.0f - g0;
        }
    }
}

extern "C" void kernel_launch(void* const* d_in, const int* in_sizes, int n_in,
                              void* d_out, int out_size, void* d_ws, size_t ws_size,
                              hipStream_t stream) {
    const float* x = (const float*)d_in[0];   // [8192, 4096] fp32
    const float* W = (const float*)d_in[1];   // [64, 4096] fp32
    float* out     = (float*)d_out;           // [4 * 8192] fp32
    _Float16* WF   = (_Float16*)d_ws;                     // 1 MB fragments
    float* P       = (float*)((char*)d_ws + (1 << 20));   // 16 MB partials

    prep_w_kernel<<<128, 256, 0, stream>>>(W, WF);
    logits_kernel<<<512, 512, 0, stream>>>(x, WF, P);
    reduce_topk_kernel<<<512, 256, 0, stream>>>(P, out);
}